// Round 7
// baseline (60.869 us; speedup 1.0000x reference)
//
#include <hip/hip_runtime.h>

// YOLOv1 loss, fused. Round-6 lesson: LDS box-scatter kept load duty-cycle at
// ~57% (3.6 of 6.3 TB/s). This version: phase A = pure coalesced float4 stream
// (class loss + per-cell unmasked sums in tiny Lcls via LDS atomics); phase B =
// re-read box region from global (L2-hot, just streamed) with scattered float2.
// No Lbox, no scatter conditionals, ~2KB LDS -> wave-slot-capped occupancy.

constexpr int SS  = 14;
constexpr int TPB = 256;
constexpr int CPT = 512;             // cells per block
constexpr int NCH = CPT * 30 / 4;    // 3840 float4 chunks per tensor per block

__device__ __forceinline__ void box_loss(
    float p0, float p1, float p2, float p3, float p4,
    float p5, float p6, float p7, float p8, float p9,
    float t0, float t1, float t2, float t3, float t4,
    float offx, float offy,
    float& s0, float& s1, float& s2, float& s3, float& m_out)
{
    float m  = (t4 == 1.0f) ? 1.0f : 0.0f;
    float nm = (t4 == 0.0f) ? 1.0f : 0.0f;
    m_out = m;

    const float S = 14.0f;
    float tcx = t0 / S + offx / S;
    float tcy = t1 / S + offy / S;
    float thw = 0.5f * t2, thh = 0.5f * t3;
    float tx0 = tcx - thw, ty0 = tcy - thh;
    float tx1 = tcx + thw, ty1 = tcy + thh;
    float area_t = t2 * t3;

    float iou0, iou1;
    {
        float cx = p0 / S + offx / S, cy = p1 / S + offy / S;
        float hw = 0.5f * p2, hh = 0.5f * p3;
        float x0 = cx - hw, y0 = cy - hh, x1 = cx + hw, y1 = cy + hh;
        float wx = fmaxf(fminf(tx1, x1) - fmaxf(tx0, x0), 0.f);
        float wy = fmaxf(fminf(ty1, y1) - fmaxf(ty0, y0), 0.f);
        float inter = wx * wy;
        iou0 = inter / (area_t + p2 * p3 - inter);
    }
    {
        float cx = p5 / S + offx / S, cy = p6 / S + offy / S;
        float hw = 0.5f * p7, hh = 0.5f * p8;
        float x0 = cx - hw, y0 = cy - hh, x1 = cx + hw, y1 = cy + hh;
        float wx = fmaxf(fminf(tx1, x1) - fmaxf(tx0, x0), 0.f);
        float wy = fmaxf(fminf(ty1, y1) - fmaxf(ty0, y0), 0.f);
        float inter = wx * wy;
        iou1 = inter / (area_t + p7 * p8 - inter);
    }

    int k = (iou1 > iou0) ? 1 : 0;     // jnp.argmax first-max tie-break
    float b0 = k ? p5 : p0, b1 = k ? p6 : p1;
    float b2 = k ? p7 : p2, b3 = k ? p8 : p3, b4 = k ? p9 : p4;
    float biou = k ? iou1 : iou0;

    float d0 = t0 - b0, d1 = t1 - b1;
    s0 += m * (d0 * d0 + d1 * d1);

    float e0 = sqrtf(t2) - sqrtf(b2);
    float e1 = sqrtf(t3) - sqrtf(b3);
    s1 += m * (e0 * e0 + e1 * e1);

    float dc = biou - b4;
    s2 += m * dc * dc;

    float conf_other = k ? p4 : p9;
    s3 += nm * (p4 * p4 + p9 * p9) + m * conf_other * conf_other;
}

__global__ __launch_bounds__(TPB) void yolo_fused(
    const float* __restrict__ pred,
    const float* __restrict__ targ,
    float4* __restrict__ partA,   // per-block {xy, wh, Cobj, Cnoobj}
    float*  __restrict__ partB)   // per-block cls
{
    __shared__ float Lcls[CPT];        // unmasked per-cell class sum

    const int tid = threadIdx.x;
    Lcls[tid] = 0.f;
    Lcls[tid + 256] = 0.f;
    __syncthreads();

    const size_t base4 = (size_t)blockIdx.x * NCH;
    const float4* P4 = reinterpret_cast<const float4*>(pred) + base4;
    const float4* T4 = reinterpret_cast<const float4*>(targ) + base4;

    // ---- phase A: coalesced stream, class components + Lcls ----
#pragma unroll
    for (int k = 0; k < 15; ++k) {
        int idx = k * TPB + tid;
        float4 pv = P4[idx];
        float4 tv = T4[idx];
        unsigned l    = 4u * (unsigned)idx;
        unsigned cell = l / 30u;
        unsigned e    = l - 30u * cell;          // even, 0..28
        float clsum = 0.f;
        float d;
        d = tv.x - pv.x; if ((unsigned)(e + 0u - 10u) < 20u) clsum += d * d;
        d = tv.y - pv.y; if ((unsigned)(e + 1u - 10u) < 20u) clsum += d * d;
        d = tv.z - pv.z; if ((unsigned)(e + 2u - 10u) < 20u) clsum += d * d;
        d = tv.w - pv.w; if ((unsigned)(e + 3u - 10u) < 20u) clsum += d * d;
        // class elems (10..29) never wrap into the next cell; e==28 z/w belong
        // to next cell elems 0,1 -> predicate already excludes them.
        if (e >= 8u) atomicAdd(&Lcls[cell], clsum);
    }

    // ---- phase B: issue box re-reads (L2-hot) BEFORE the barrier ----
    const float2* p2g = reinterpret_cast<const float2*>(pred);
    const float2* t2g = reinterpret_cast<const float2*>(targ);
    unsigned gc0 = (unsigned)blockIdx.x * CPT + (unsigned)tid;        // h=0
    unsigned gc1 = gc0 + 256u;                                       // h=1
    const float2* pA = p2g + (size_t)gc0 * 15u;
    const float2* tA = t2g + (size_t)gc0 * 15u;
    const float2* pB = p2g + (size_t)gc1 * 15u;
    const float2* tB = t2g + (size_t)gc1 * 15u;
    float2 a0 = pA[0], a1 = pA[1], a2 = pA[2], a3 = pA[3], a4 = pA[4];
    float2 u0 = tA[0], u1 = tA[1];
    float  w4A = targ[(size_t)gc0 * 30u + 4u];
    float2 b0 = pB[0], b1 = pB[1], b2 = pB[2], b3 = pB[3], b4 = pB[4];
    float2 v0 = tB[0], v1 = tB[1];
    float  w4B = targ[(size_t)gc1 * 30u + 4u];

    __syncthreads();   // Lcls complete (phase-B loads already in flight)

    float s0 = 0.f, s1 = 0.f, s2 = 0.f, s3 = 0.f, s4 = 0.f;
    {
        unsigned ij = gc0 % 196u;
        float offx = (float)(ij % 14u);   // off = (j, i): x = column
        float offy = (float)(ij / 14u);
        float m;
        box_loss(a0.x, a0.y, a1.x, a1.y, a2.x, a2.y, a3.x, a3.y, a4.x, a4.y,
                 u0.x, u0.y, u1.x, u1.y, w4A, offx, offy, s0, s1, s2, s3, m);
        s4 += m * Lcls[tid];
    }
    {
        unsigned ij = gc1 % 196u;
        float offx = (float)(ij % 14u);
        float offy = (float)(ij / 14u);
        float m;
        box_loss(b0.x, b0.y, b1.x, b1.y, b2.x, b2.y, b3.x, b3.y, b4.x, b4.y,
                 v0.x, v0.y, v1.x, v1.y, w4B, offx, offy, s0, s1, s2, s3, m);
        s4 += m * Lcls[tid + 256];
    }

    // ---- wave butterfly reduce ----
#pragma unroll
    for (int o = 32; o > 0; o >>= 1) {
        s0 += __shfl_down(s0, o);
        s1 += __shfl_down(s1, o);
        s2 += __shfl_down(s2, o);
        s3 += __shfl_down(s3, o);
        s4 += __shfl_down(s4, o);
    }

    __shared__ float red[4][5];
    int wave = tid >> 6;
    if ((tid & 63) == 0) {
        red[wave][0] = s0; red[wave][1] = s1; red[wave][2] = s2;
        red[wave][3] = s3; red[wave][4] = s4;
    }
    __syncthreads();
    if (tid == 0) {
        partA[blockIdx.x] = make_float4(
            red[0][0] + red[1][0] + red[2][0] + red[3][0],
            red[0][1] + red[1][1] + red[2][1] + red[3][1],
            red[0][2] + red[1][2] + red[2][2] + red[3][2],
            red[0][3] + red[1][3] + red[2][3] + red[3][3]);
        partB[blockIdx.x] =
            red[0][4] + red[1][4] + red[2][4] + red[3][4];
    }
}

__global__ __launch_bounds__(256) void yolo_final(
    const float4* __restrict__ partA, int nA,
    const float* __restrict__ partB,
    float* __restrict__ out, float invN)
{
    float a0 = 0.f, a1 = 0.f, a2 = 0.f, a3 = 0.f, b = 0.f;
    for (int i = threadIdx.x; i < nA; i += 256) {
        float4 v = partA[i];
        a0 += v.x; a1 += v.y; a2 += v.z; a3 += v.w;
        b += partB[i];
    }
#pragma unroll
    for (int o = 32; o > 0; o >>= 1) {
        a0 += __shfl_down(a0, o);
        a1 += __shfl_down(a1, o);
        a2 += __shfl_down(a2, o);
        a3 += __shfl_down(a3, o);
        b  += __shfl_down(b, o);
    }
    __shared__ float red[4][5];
    int wave = threadIdx.x >> 6;
    if ((threadIdx.x & 63) == 0) {
        red[wave][0] = a0; red[wave][1] = a1; red[wave][2] = a2;
        red[wave][3] = a3; red[wave][4] = b;
    }
    __syncthreads();
    if (threadIdx.x == 0) {
        float xy     = (red[0][0]+red[1][0]+red[2][0]+red[3][0]) * 5.0f * invN;
        float wh     = (red[0][1]+red[1][1]+red[2][1]+red[3][1]) * 5.0f * invN;
        float cobj   = (red[0][2]+red[1][2]+red[2][2]+red[3][2]) * invN;
        float cnoobj = (red[0][3]+red[1][3]+red[2][3]+red[3][3]) * 0.5f * invN;
        float cls    = (red[0][4]+red[1][4]+red[2][4]+red[3][4]) * invN;
        out[0] = xy + wh + cobj + cnoobj + cls;
        out[1] = xy;
        out[2] = wh;
        out[3] = cobj;
        out[4] = cnoobj;
        out[5] = cls;
    }
}

extern "C" void kernel_launch(void* const* d_in, const int* in_sizes, int n_in,
                              void* d_out, int out_size, void* d_ws, size_t ws_size,
                              hipStream_t stream)
{
    const float* pred = (const float*)d_in[0];
    const float* targ = (const float*)d_in[1];
    int ncells = in_sizes[0] / 30;             // 802816
    int blocks = ncells / CPT;                 // 1568 exact
    int N      = ncells / (SS * SS);

    float4* partA = (float4*)d_ws;
    float*  partB = (float*)((char*)d_ws + (size_t)blocks * sizeof(float4));

    yolo_fused<<<blocks, TPB, 0, stream>>>(pred, targ, partA, partB);
    yolo_final<<<1, 256, 0, stream>>>(partA, blocks, partB,
                                      (float*)d_out, 1.0f / (float)N);
}

// Round 8
// 58.658 us; speedup vs baseline: 1.0377x; 1.0377x over previous
//
#include <hip/hip_runtime.h>

// YOLOv1 loss, fused, LDS box-gather (round-6 structure), occupancy-reshaped.
// Round-7 lesson: phase-B global re-reads thrash L2 (FETCH 94->179MB) - reuse
// must live in LDS. Round-6 lesson: 1568x256t blocks left CUs half-empty.
// Here: 128-thread / 128-cell blocks (8.2KB LDS) -> 16 blocks/CU resident,
// grid 6272 keeps the machine full. Math byte-identical to verified round 6.

constexpr int SS  = 14;
constexpr int TPB = 128;
constexpr int CPT = 128;             // cells per tile
constexpr int NCH = CPT * 30 / 4;    // 960 float4 chunks per tensor per tile

__device__ __forceinline__ void box_loss(
    float p0, float p1, float p2, float p3, float p4,
    float p5, float p6, float p7, float p8, float p9,
    float t0, float t1, float t2, float t3, float t4,
    float offx, float offy,
    float& s0, float& s1, float& s2, float& s3, float& m_out)
{
    float m  = (t4 == 1.0f) ? 1.0f : 0.0f;
    float nm = (t4 == 0.0f) ? 1.0f : 0.0f;
    m_out = m;

    const float S = 14.0f;
    float tcx = t0 / S + offx / S;
    float tcy = t1 / S + offy / S;
    float thw = 0.5f * t2, thh = 0.5f * t3;
    float tx0 = tcx - thw, ty0 = tcy - thh;
    float tx1 = tcx + thw, ty1 = tcy + thh;
    float area_t = t2 * t3;

    float iou0, iou1;
    {
        float cx = p0 / S + offx / S, cy = p1 / S + offy / S;
        float hw = 0.5f * p2, hh = 0.5f * p3;
        float x0 = cx - hw, y0 = cy - hh, x1 = cx + hw, y1 = cy + hh;
        float wx = fmaxf(fminf(tx1, x1) - fmaxf(tx0, x0), 0.f);
        float wy = fmaxf(fminf(ty1, y1) - fmaxf(ty0, y0), 0.f);
        float inter = wx * wy;
        iou0 = inter / (area_t + p2 * p3 - inter);
    }
    {
        float cx = p5 / S + offx / S, cy = p6 / S + offy / S;
        float hw = 0.5f * p7, hh = 0.5f * p8;
        float x0 = cx - hw, y0 = cy - hh, x1 = cx + hw, y1 = cy + hh;
        float wx = fmaxf(fminf(tx1, x1) - fmaxf(tx0, x0), 0.f);
        float wy = fmaxf(fminf(ty1, y1) - fmaxf(ty0, y0), 0.f);
        float inter = wx * wy;
        iou1 = inter / (area_t + p7 * p8 - inter);
    }

    int k = (iou1 > iou0) ? 1 : 0;     // jnp.argmax first-max tie-break
    float b0 = k ? p5 : p0, b1 = k ? p6 : p1;
    float b2 = k ? p7 : p2, b3 = k ? p8 : p3, b4 = k ? p9 : p4;
    float biou = k ? iou1 : iou0;

    float d0 = t0 - b0, d1 = t1 - b1;
    s0 += m * (d0 * d0 + d1 * d1);

    float e0 = sqrtf(t2) - sqrtf(b2);
    float e1 = sqrtf(t3) - sqrtf(b3);
    s1 += m * (e0 * e0 + e1 * e1);

    float dc = biou - b4;
    s2 += m * dc * dc;

    float conf_other = k ? p4 : p9;
    s3 += nm * (p4 * p4 + p9 * p9) + m * conf_other * conf_other;
}

__global__ __launch_bounds__(TPB) void yolo_fused(
    const float* __restrict__ pred,
    const float* __restrict__ targ,
    float4* __restrict__ partA,   // per-block {xy, wh, Cobj, Cnoobj}
    float*  __restrict__ partB,   // per-block cls
    int ntiles)
{
    __shared__ float Lbox[CPT * 15];   // 0..9 pred box, 10..14 targ box (14 = t4)
    __shared__ float Lcls[CPT];        // unmasked per-cell class sum

    const int tid = threadIdx.x;
    float s0 = 0.f, s1 = 0.f, s2 = 0.f, s3 = 0.f, s4 = 0.f;

#pragma unroll 1
    for (int tile = 0; tile < ntiles; ++tile) {
        if (tile) __syncthreads();            // protect LDS reuse across tiles
        Lcls[tid] = 0.f;
        __syncthreads();

        const size_t tbase = (size_t)blockIdx.x * ntiles + tile;
        const float4* P = reinterpret_cast<const float4*>(pred) + tbase * NCH;
        const float4* T = reinterpret_cast<const float4*>(targ) + tbase * NCH;

        // coalesced loads: lane i -> consecutive 16B
#pragma unroll
        for (int k = 0; k < 8; ++k) {
            int idx = k * TPB + tid;
            if (idx < NCH) {                  // only k==7 partially active
                float4 pv = P[idx];
                float4 tv = T[idx];
                unsigned l    = 4u * (unsigned)idx;
                unsigned cell = l / 30u;
                unsigned e    = l - 30u * cell;  // even, 0..28
                float pc[4] = { pv.x, pv.y, pv.z, pv.w };
                float tc[4] = { tv.x, tv.y, tv.z, tv.w };
                float clsum = 0.f;
#pragma unroll
                for (int j = 0; j < 4; ++j) {
                    unsigned ej = e + j, c2 = cell;
                    if (ej >= 30u) { ej -= 30u; c2 += 1u; }   // only e==28, j>=2
                    if (ej < 10u) Lbox[c2 * 15u + ej] = pc[j];
                    if (ej < 5u)  Lbox[c2 * 15u + 10u + ej] = tc[j];
                    if (ej >= 10u) { float d = tc[j] - pc[j]; clsum += d * d; }
                }
                if (e >= 8u) atomicAdd(&Lcls[cell], clsum);   // class never wraps cells
            }
        }
        __syncthreads();

        // phase 2: one cell per thread from LDS (stride 15 odd -> conflict-free)
        {
            const float* Bx = &Lbox[tid * 15];
            float p0 = Bx[0], p1 = Bx[1], p2 = Bx[2], p3 = Bx[3], p4 = Bx[4];
            float p5 = Bx[5], p6 = Bx[6], p7 = Bx[7], p8 = Bx[8], p9 = Bx[9];
            float t0 = Bx[10], t1 = Bx[11], t2 = Bx[12], t3 = Bx[13], t4 = Bx[14];

            unsigned gcell = (unsigned)tbase * CPT + (unsigned)tid;
            unsigned ij = gcell % 196u;
            float offx = (float)(ij % 14u);   // off = (j, i): x = column
            float offy = (float)(ij / 14u);

            float m;
            box_loss(p0, p1, p2, p3, p4, p5, p6, p7, p8, p9,
                     t0, t1, t2, t3, t4, offx, offy, s0, s1, s2, s3, m);
            s4 += m * Lcls[tid];
        }
    }

    // wave butterfly reduce (2 waves per block)
#pragma unroll
    for (int o = 32; o > 0; o >>= 1) {
        s0 += __shfl_down(s0, o);
        s1 += __shfl_down(s1, o);
        s2 += __shfl_down(s2, o);
        s3 += __shfl_down(s3, o);
        s4 += __shfl_down(s4, o);
    }

    __shared__ float red[2][5];
    int wave = tid >> 6;
    if ((tid & 63) == 0) {
        red[wave][0] = s0; red[wave][1] = s1; red[wave][2] = s2;
        red[wave][3] = s3; red[wave][4] = s4;
    }
    __syncthreads();
    if (tid == 0) {
        partA[blockIdx.x] = make_float4(
            red[0][0] + red[1][0],
            red[0][1] + red[1][1],
            red[0][2] + red[1][2],
            red[0][3] + red[1][3]);
        partB[blockIdx.x] = red[0][4] + red[1][4];
    }
}

__global__ __launch_bounds__(256) void yolo_final(
    const float4* __restrict__ partA, int nA,
    const float* __restrict__ partB,
    float* __restrict__ out, float invN)
{
    float a0 = 0.f, a1 = 0.f, a2 = 0.f, a3 = 0.f, b = 0.f;
    for (int i = threadIdx.x; i < nA; i += 256) {
        float4 v = partA[i];
        a0 += v.x; a1 += v.y; a2 += v.z; a3 += v.w;
        b += partB[i];
    }
#pragma unroll
    for (int o = 32; o > 0; o >>= 1) {
        a0 += __shfl_down(a0, o);
        a1 += __shfl_down(a1, o);
        a2 += __shfl_down(a2, o);
        a3 += __shfl_down(a3, o);
        b  += __shfl_down(b, o);
    }
    __shared__ float red[4][5];
    int wave = threadIdx.x >> 6;
    if ((threadIdx.x & 63) == 0) {
        red[wave][0] = a0; red[wave][1] = a1; red[wave][2] = a2;
        red[wave][3] = a3; red[wave][4] = b;
    }
    __syncthreads();
    if (threadIdx.x == 0) {
        float xy     = (red[0][0]+red[1][0]+red[2][0]+red[3][0]) * 5.0f * invN;
        float wh     = (red[0][1]+red[1][1]+red[2][1]+red[3][1]) * 5.0f * invN;
        float cobj   = (red[0][2]+red[1][2]+red[2][2]+red[3][2]) * invN;
        float cnoobj = (red[0][3]+red[1][3]+red[2][3]+red[3][3]) * 0.5f * invN;
        float cls    = (red[0][4]+red[1][4]+red[2][4]+red[3][4]) * invN;
        out[0] = xy + wh + cobj + cnoobj + cls;
        out[1] = xy;
        out[2] = wh;
        out[3] = cobj;
        out[4] = cnoobj;
        out[5] = cls;
    }
}

extern "C" void kernel_launch(void* const* d_in, const int* in_sizes, int n_in,
                              void* d_out, int out_size, void* d_ws, size_t ws_size,
                              hipStream_t stream)
{
    const float* pred = (const float*)d_in[0];
    const float* targ = (const float*)d_in[1];
    int ncells  = in_sizes[0] / 30;            // 802816
    int ttiles  = ncells / CPT;                // 6272 total tiles
    int N       = ncells / (SS * SS);

    // pick tiles-per-block so per-block partials fit in d_ws (20B per block)
    int ntiles = 1;
    while ((size_t)(ttiles / ntiles) * 20 + 16 > ws_size && ntiles < 64) ntiles *= 2;
    int blocks = ttiles / ntiles;

    float4* partA = (float4*)d_ws;
    float*  partB = (float*)((char*)d_ws + (size_t)blocks * sizeof(float4));

    yolo_fused<<<blocks, TPB, 0, stream>>>(pred, targ, partA, partB, ntiles);
    yolo_final<<<1, 256, 0, stream>>>(partA, blocks, partB,
                                      (float*)d_out, 1.0f / (float)N);
}

// Round 9
// 39.226 us; speedup vs baseline: 1.5518x; 1.4954x over previous
//
#include <hip/hip_runtime.h>

// YOLOv1 loss, DMA-staged. Round-8 lesson: exec-masked LDS scatter is ~300
// VALU/cell - every scatter variant converges to ~56-60us. This version:
// global_load_lds stages the tile RAW (linear, zero VALU, zero VGPR traffic);
// one thread per cell-PAIR (240B = 15 float4, 16B aligned) reads chunks with
// COMPILE-TIME roles (no predicates/mods). 1 wave/block -> no barriers at all;
// LDS visibility within the wave needs only s_waitcnt vmcnt(0). No atomics.

constexpr int SS  = 14;
constexpr int TPB = 64;                  // one wave
constexpr int CPT = 128;                 // cells per tile (= 64 pairs)
constexpr int TFL = CPT * 30;            // floats per tensor per tile = 3840
constexpr int NLD = TFL / 256;           // 15 x 1KB global_load_lds per tensor

typedef unsigned int u32;
typedef __attribute__((address_space(3))) u32 lds_u32;
typedef __attribute__((address_space(1))) const u32 glb_u32;

__device__ __forceinline__ void box_loss(
    float p0, float p1, float p2, float p3, float p4,
    float p5, float p6, float p7, float p8, float p9,
    float t0, float t1, float t2, float t3, float t4,
    float offx, float offy,
    float& s0, float& s1, float& s2, float& s3, float& m_out)
{
    float m  = (t4 == 1.0f) ? 1.0f : 0.0f;
    float nm = (t4 == 0.0f) ? 1.0f : 0.0f;
    m_out = m;

    const float S = 14.0f;
    float tcx = t0 / S + offx / S;
    float tcy = t1 / S + offy / S;
    float thw = 0.5f * t2, thh = 0.5f * t3;
    float tx0 = tcx - thw, ty0 = tcy - thh;
    float tx1 = tcx + thw, ty1 = tcy + thh;
    float area_t = t2 * t3;

    float iou0, iou1;
    {
        float cx = p0 / S + offx / S, cy = p1 / S + offy / S;
        float hw = 0.5f * p2, hh = 0.5f * p3;
        float x0 = cx - hw, y0 = cy - hh, x1 = cx + hw, y1 = cy + hh;
        float wx = fmaxf(fminf(tx1, x1) - fmaxf(tx0, x0), 0.f);
        float wy = fmaxf(fminf(ty1, y1) - fmaxf(ty0, y0), 0.f);
        float inter = wx * wy;
        iou0 = inter / (area_t + p2 * p3 - inter);
    }
    {
        float cx = p5 / S + offx / S, cy = p6 / S + offy / S;
        float hw = 0.5f * p7, hh = 0.5f * p8;
        float x0 = cx - hw, y0 = cy - hh, x1 = cx + hw, y1 = cy + hh;
        float wx = fmaxf(fminf(tx1, x1) - fmaxf(tx0, x0), 0.f);
        float wy = fmaxf(fminf(ty1, y1) - fmaxf(ty0, y0), 0.f);
        float inter = wx * wy;
        iou1 = inter / (area_t + p7 * p8 - inter);
    }

    int k = (iou1 > iou0) ? 1 : 0;     // jnp.argmax first-max tie-break
    float b0 = k ? p5 : p0, b1 = k ? p6 : p1;
    float b2 = k ? p7 : p2, b3 = k ? p8 : p3, b4 = k ? p9 : p4;
    float biou = k ? iou1 : iou0;

    float d0 = t0 - b0, d1 = t1 - b1;
    s0 += m * (d0 * d0 + d1 * d1);

    float e0 = sqrtf(t2) - sqrtf(b2);
    float e1 = sqrtf(t3) - sqrtf(b3);
    s1 += m * (e0 * e0 + e1 * e1);

    float dc = biou - b4;
    s2 += m * dc * dc;

    float conf_other = k ? p4 : p9;
    s3 += nm * (p4 * p4 + p9 * p9) + m * conf_other * conf_other;
}

__global__ __launch_bounds__(TPB) void yolo_fused(
    const float* __restrict__ pred,
    const float* __restrict__ targ,
    float4* __restrict__ partA,   // per-block {xy, wh, Cobj, Cnoobj}
    float*  __restrict__ partB,   // per-block cls
    int ntiles)
{
    __shared__ __align__(16) float Lraw[2 * TFL];   // [0,TFL): pred, [TFL,2TFL): targ
    const int lane = threadIdx.x;

    float s0 = 0.f, s1 = 0.f, s2 = 0.f, s3 = 0.f, s4 = 0.f;

#pragma unroll 1
    for (int tile = 0; tile < ntiles; ++tile) {
        const size_t tb = (size_t)blockIdx.x * ntiles + tile;
        const float* ps = pred + tb * TFL;
        const float* ts = targ + tb * TFL;

        // previous tile's ds_reads must drain before DMA overwrites LDS
        if (tile) asm volatile("s_waitcnt lgkmcnt(0)" ::: "memory");

        // ---- phase A: raw DMA stage, no VGPR round-trip, no scatter ----
#pragma unroll
        for (int i = 0; i < NLD; ++i)
            __builtin_amdgcn_global_load_lds((glb_u32*)(ps + i * 256 + lane * 4),
                                             (lds_u32*)&Lraw[i * 256], 16, 0, 0);
#pragma unroll
        for (int i = 0; i < NLD; ++i)
            __builtin_amdgcn_global_load_lds((glb_u32*)(ts + i * 256 + lane * 4),
                                             (lds_u32*)&Lraw[TFL + i * 256], 16, 0, 0);
        asm volatile("s_waitcnt vmcnt(0)" ::: "memory");
        __builtin_amdgcn_sched_barrier(0);
        // single wave per block: lanes see their own wave's LDS, no s_barrier

        // ---- phase B: one PAIR per lane, compile-time chunk roles ----
        const float4* Pf = reinterpret_cast<const float4*>(Lraw) + lane * 15;
        const float4* Tf = reinterpret_cast<const float4*>(Lraw + TFL) + lane * 15;
        float4 P0=Pf[0],P1=Pf[1],P2=Pf[2],P3=Pf[3],P4=Pf[4],P5=Pf[5],P6=Pf[6],
               P7=Pf[7],P8=Pf[8],P9=Pf[9],P10=Pf[10],P11=Pf[11],P12=Pf[12],
               P13=Pf[13],P14=Pf[14];
        float4 T0=Tf[0],T1=Tf[1],T2=Tf[2],T3=Tf[3],T4=Tf[4],T5=Tf[5],T6=Tf[6],
               T7=Tf[7],T8=Tf[8],T10=Tf[10],T11=Tf[11],T12=Tf[12],T13=Tf[13],
               T14=Tf[14];                      // T9 (pair elems 36..39) unused

        unsigned gcell0 = (unsigned)tb * CPT + 2u * (unsigned)lane;  // even
        unsigned ij = gcell0 % 196u;
        float offx = (float)(ij % 14u);   // off = (j, i): x = column
        float offy = (float)(ij / 14u);   // even cell -> pair never wraps a row

        float m0, m1;
        // cell0: pred elems 0..9 = P0,P1,P2.xy ; targ 0..4 = T0,T1.x
        box_loss(P0.x,P0.y,P0.z,P0.w,P1.x,P1.y,P1.z,P1.w,P2.x,P2.y,
                 T0.x,T0.y,T0.z,T0.w,T1.x, offx, offy, s0,s1,s2,s3, m0);
        // cell1: pred elems 30..39 = P7.zw,P8,P9 ; targ 30..34 = T7.zw,T8.xyz
        box_loss(P7.z,P7.w,P8.x,P8.y,P8.z,P8.w,P9.x,P9.y,P9.z,P9.w,
                 T7.z,T7.w,T8.x,T8.y,T8.z, offx + 1.0f, offy, s0,s1,s2,s3, m1);

        // class: cell0 elems 10..29 ; cell1 elems 40..59 (ascending order)
        float c0 = 0.f, c1 = 0.f, d;
        d=T2.z-P2.z; c0+=d*d;  d=T2.w-P2.w; c0+=d*d;
        d=T3.x-P3.x; c0+=d*d;  d=T3.y-P3.y; c0+=d*d;
        d=T3.z-P3.z; c0+=d*d;  d=T3.w-P3.w; c0+=d*d;
        d=T4.x-P4.x; c0+=d*d;  d=T4.y-P4.y; c0+=d*d;
        d=T4.z-P4.z; c0+=d*d;  d=T4.w-P4.w; c0+=d*d;
        d=T5.x-P5.x; c0+=d*d;  d=T5.y-P5.y; c0+=d*d;
        d=T5.z-P5.z; c0+=d*d;  d=T5.w-P5.w; c0+=d*d;
        d=T6.x-P6.x; c0+=d*d;  d=T6.y-P6.y; c0+=d*d;
        d=T6.z-P6.z; c0+=d*d;  d=T6.w-P6.w; c0+=d*d;
        d=T7.x-P7.x; c0+=d*d;  d=T7.y-P7.y; c0+=d*d;

        d=T10.x-P10.x; c1+=d*d;  d=T10.y-P10.y; c1+=d*d;
        d=T10.z-P10.z; c1+=d*d;  d=T10.w-P10.w; c1+=d*d;
        d=T11.x-P11.x; c1+=d*d;  d=T11.y-P11.y; c1+=d*d;
        d=T11.z-P11.z; c1+=d*d;  d=T11.w-P11.w; c1+=d*d;
        d=T12.x-P12.x; c1+=d*d;  d=T12.y-P12.y; c1+=d*d;
        d=T12.z-P12.z; c1+=d*d;  d=T12.w-P12.w; c1+=d*d;
        d=T13.x-P13.x; c1+=d*d;  d=T13.y-P13.y; c1+=d*d;
        d=T13.z-P13.z; c1+=d*d;  d=T13.w-P13.w; c1+=d*d;
        d=T14.x-P14.x; c1+=d*d;  d=T14.y-P14.y; c1+=d*d;
        d=T14.z-P14.z; c1+=d*d;  d=T14.w-P14.w; c1+=d*d;

        s4 += m0 * c0 + m1 * c1;
    }

    // ---- single-wave butterfly reduce, no LDS / no barrier ----
#pragma unroll
    for (int o = 32; o > 0; o >>= 1) {
        s0 += __shfl_down(s0, o);
        s1 += __shfl_down(s1, o);
        s2 += __shfl_down(s2, o);
        s3 += __shfl_down(s3, o);
        s4 += __shfl_down(s4, o);
    }
    if (lane == 0) {
        partA[blockIdx.x] = make_float4(s0, s1, s2, s3);
        partB[blockIdx.x] = s4;
    }
}

__global__ __launch_bounds__(1024) void yolo_final(
    const float4* __restrict__ partA, int nA,
    const float* __restrict__ partB,
    float* __restrict__ out, float invN)
{
    float a0 = 0.f, a1 = 0.f, a2 = 0.f, a3 = 0.f, b = 0.f;
    for (int i = threadIdx.x; i < nA; i += 1024) {
        float4 v = partA[i];
        a0 += v.x; a1 += v.y; a2 += v.z; a3 += v.w;
        b += partB[i];
    }
#pragma unroll
    for (int o = 32; o > 0; o >>= 1) {
        a0 += __shfl_down(a0, o);
        a1 += __shfl_down(a1, o);
        a2 += __shfl_down(a2, o);
        a3 += __shfl_down(a3, o);
        b  += __shfl_down(b, o);
    }
    __shared__ float red[16][5];
    int wave = threadIdx.x >> 6;
    if ((threadIdx.x & 63) == 0) {
        red[wave][0] = a0; red[wave][1] = a1; red[wave][2] = a2;
        red[wave][3] = a3; red[wave][4] = b;
    }
    __syncthreads();
    if (threadIdx.x == 0) {
        float r0=0, r1=0, r2=0, r3=0, r4=0;
#pragma unroll
        for (int w = 0; w < 16; ++w) {
            r0 += red[w][0]; r1 += red[w][1]; r2 += red[w][2];
            r3 += red[w][3]; r4 += red[w][4];
        }
        float xy     = r0 * 5.0f * invN;
        float wh     = r1 * 5.0f * invN;
        float cobj   = r2 * invN;
        float cnoobj = r3 * 0.5f * invN;
        float cls    = r4 * invN;
        out[0] = xy + wh + cobj + cnoobj + cls;
        out[1] = xy;
        out[2] = wh;
        out[3] = cobj;
        out[4] = cnoobj;
        out[5] = cls;
    }
}

extern "C" void kernel_launch(void* const* d_in, const int* in_sizes, int n_in,
                              void* d_out, int out_size, void* d_ws, size_t ws_size,
                              hipStream_t stream)
{
    const float* pred = (const float*)d_in[0];
    const float* targ = (const float*)d_in[1];
    int ncells = in_sizes[0] / 30;            // 802816
    int ttiles = ncells / CPT;                // 6272 tiles
    int N      = ncells / (SS * SS);

    // tiles-per-block so per-block partials (20B) fit in d_ws
    int ntiles = 1;
    while ((size_t)(ttiles / ntiles) * 20 + 16 > ws_size && ntiles < 64) ntiles *= 2;
    int blocks = ttiles / ntiles;

    float4* partA = (float4*)d_ws;
    float*  partB = (float*)((char*)d_ws + (size_t)blocks * sizeof(float4));

    yolo_fused<<<blocks, TPB, 0, stream>>>(pred, targ, partA, partB, ntiles);
    yolo_final<<<1, 1024, 0, stream>>>(partA, blocks, partB,
                                       (float*)d_out, 1.0f / (float)N);
}